// Round 8
// baseline (197.311 us; speedup 1.0000x reference)
//
#include <hip/hip_runtime.h>
#include <hip/hip_bf16.h>

// RecognitionLattice: RNN-T style lattice loss.
// k_front: fproj GEMM (direct fp32-Wf transpose staging, f16 out) + Wo->fp8
//          shuffle (144-slot g-planes, XOR bank swizzle) + cemb gather (f16)
// -> k_joint: h=tanh(fproj+cemb) packed-f16 -> fp8 @ Wo_fp8, BK=64 K-loop.
//    4-wave blocks (64-row tiles), A-frags in registers, B double-buffered
//    via global_load_lds, read as SWIZZLED ds_read_b128 pairs (quad ^= row&7;
//    g-plane stride 144 slots makes row&7 injective over (g, c>>3) -> 2-way
//    max aliasing = free). Base-2 epilogue, 16B cl store.
// -> k_compact: parallel depth-4 semiring compaction (base-2 f16x2 in) -> Dg
// -> k_dpser: 1 wave/batch serial chain, 128 banded-lse5 steps, Dg staged
//    through LDS (8-group chunks, triple-buffered, counted vmcnt(20)).

#define BB 4
#define TT 512
#define UU 96
#define FF 512
#define HH 512
#define VV 256
#define NV (VV + 1)    // 257 vocab incl. blank
#define NEG_INF (-1e30f)
#define LOG2E 1.4426950408889634f
#define LN2 0.6931471805599453f
#define NG 128         // groups of 4 t-steps
#define GSTRIDE 640    // padded floats per group operator (2560B; data in 0..519)
#define WOSCL 64.0f    // Wo pre-scale into fp8 normal range
#define C2SCL 0.022542110f  // log2(e)/64: descale+base2 fold for the LSE
#define NU 97          // lattice rows per t
#define BCHUNK 18432   // bytes per 64-k B chunk (2 sub x 4 g x 144 slots x 16B)
#define BLONGS 2304    // longs per chunk
#define CHG 8                      // dpser: groups per staged chunk
#define CHB (CHG * GSTRIDE * 4)    // 20480 bytes per chunk
#define CHI (CHB / 1024)           // 20 async copies per chunk
#define CHF (CHG * GSTRIDE)        // floats per chunk buffer

typedef _Float16 f16;
typedef __attribute__((ext_vector_type(2))) _Float16 f16x2;
typedef __attribute__((ext_vector_type(8))) _Float16 f16x8;
typedef __attribute__((ext_vector_type(2))) long longx2;
typedef __bf16 bf16;
typedef __bf16 bf16x8 __attribute__((ext_vector_type(8)));
typedef float f32x4 __attribute__((ext_vector_type(4)));

__device__ __forceinline__ f16x8 splat8(float s) {
    f16 v = (f16)s;
    f16x8 r = {v, v, v, v, v, v, v, v};
    return r;
}

// tanh via clamped odd polynomial in PACKED f16 (v_pk_* dual-issue), then
// fp8 e4m3 pack. Max poly err ~0.007 on [-2,2]; f16 intermediate err ~1e-3
// << fp8 output quantization.
__device__ __forceinline__ long tanh_pack8(f16x8 fv8, f16x8 cv8) {
    f16x8 x = fv8 + cv8;
    x = __builtin_elementwise_min(__builtin_elementwise_max(x, splat8(-2.0f)),
                                  splat8(2.0f));
    f16x8 y = x * x;
    f16x8 q = y * splat8(-0.0067528f) + splat8(0.0700672f);
    q = y * q + splat8(-0.301720f);
    q = y * q + splat8(1.0f);
    f16x8 t = x * q;
    int lo = 0, hi = 0;
    lo = __builtin_amdgcn_cvt_pk_fp8_f32((float)t[0], (float)t[1], lo, false);
    lo = __builtin_amdgcn_cvt_pk_fp8_f32((float)t[2], (float)t[3], lo, true);
    hi = __builtin_amdgcn_cvt_pk_fp8_f32((float)t[4], (float)t[5], hi, false);
    hi = __builtin_amdgcn_cvt_pk_fp8_f32((float)t[6], (float)t[7], hi, true);
    return (long)(((unsigned long long)(unsigned int)lo) |
                  (((unsigned long long)(unsigned int)hi) << 32));
}

// pack 8 floats -> 8 fp8 e4m3 (for Wo prep)
__device__ __forceinline__ long pack_fp8x8(const float* v) {
    int lo = 0, hi = 0;
    lo = __builtin_amdgcn_cvt_pk_fp8_f32(v[0], v[1], lo, false);
    lo = __builtin_amdgcn_cvt_pk_fp8_f32(v[2], v[3], lo, true);
    hi = __builtin_amdgcn_cvt_pk_fp8_f32(v[4], v[5], hi, false);
    hi = __builtin_amdgcn_cvt_pk_fp8_f32(v[6], v[7], hi, true);
    return (long)(((unsigned long long)(unsigned int)lo) |
                  (((unsigned long long)(unsigned int)hi) << 32));
}

// base-2 log-domain ops (inputs/outputs already scaled by log2(e))
__device__ __forceinline__ float lae2(float x, float y) {
    float m = fmaxf(x, y);
    float d = fminf(x, y) - m;
    return m + __builtin_amdgcn_logf(1.0f + __builtin_amdgcn_exp2f(d));
}

__device__ __forceinline__ float lse3_2(float x, float y, float z) {
    float m = fmaxf(fmaxf(x, y), z);
    float s = __builtin_amdgcn_exp2f(x - m) + __builtin_amdgcn_exp2f(y - m) +
              __builtin_amdgcn_exp2f(z - m);
    return m + __builtin_amdgcn_logf(s);
}

__device__ __forceinline__ float lse5_2(float a, float b, float c, float d, float e) {
    float m = fmaxf(fmaxf(fmaxf(a, b), fmaxf(c, d)), e);
    float s = __builtin_amdgcn_exp2f(a - m) + __builtin_amdgcn_exp2f(b - m) +
              __builtin_amdgcn_exp2f(c - m) + __builtin_amdgcn_exp2f(d - m) +
              __builtin_amdgcn_exp2f(e - m);
    return m + __builtin_amdgcn_logf(s);
}

__device__ __forceinline__ void async_copy16(const void* g, void* l) {
    __builtin_amdgcn_global_load_lds(
        (const __attribute__((address_space(1))) unsigned int*)g,
        (__attribute__((address_space(3))) unsigned int*)l, 16, 0, 0);
}

// ---- front: fproj GEMM + Wo->fp8 shuffle + cemb gather
__global__ __launch_bounds__(256, 2) void k_front(
    const float* __restrict__ frames, const float* __restrict__ Wf,
    const float* __restrict__ Wo, const float* __restrict__ E,
    const int* __restrict__ labels, f16* __restrict__ fproj,
    long* __restrict__ Wo_s, f16* __restrict__ cemb) {
    __shared__ bf16 Alds[64 * 40];
    __shared__ bf16 Blds[64 * 40];
    const int blk = blockIdx.x;
    const int tid = threadIdx.x;

    if (blk < 256) {
        const int r0 = (blk & 31) * 64;
        const int n0 = (blk >> 5) * 64;
        const int lane = tid & 63, w = tid >> 6;
        const int c = lane & 15, g = lane >> 4;

        const int srow = tid >> 2, sko = (tid & 3) * 8;
        const float* fptr = frames + (size_t)(r0 + srow) * FF + sko;
        const int q = tid >> 6, c64 = tid & 63;  // B-transpose staging coords

        f32x4 acc[4];
#pragma unroll
        for (int j = 0; j < 4; ++j) acc[j] = (f32x4){0.f, 0.f, 0.f, 0.f};

        for (int kt = 0; kt < FF; kt += 32) {
            float4 f1 = *(const float4*)(fptr + kt);
            float4 f2 = *(const float4*)(fptr + kt + 4);
            bf16x8 av = {(bf16)f1.x, (bf16)f1.y, (bf16)f1.z, (bf16)f1.w,
                         (bf16)f2.x, (bf16)f2.y, (bf16)f2.z, (bf16)f2.w};
            *(bf16x8*)&Alds[srow * 40 + sko] = av;
#pragma unroll
            for (int p = 0; p < 8; ++p) {
                float v = Wf[(size_t)(kt + q * 8 + p) * HH + n0 + c64];
                Blds[c64 * 40 + q * 8 + p] = (bf16)v;
            }
            __syncthreads();
            const int m = w * 16;
            bf16x8 af = *(const bf16x8*)&Alds[(m + c) * 40 + g * 8];
#pragma unroll
            for (int j = 0; j < 4; ++j) {
                bf16x8 bv = *(const bf16x8*)&Blds[(j * 16 + c) * 40 + g * 8];
                acc[j] = __builtin_amdgcn_mfma_f32_16x16x32_bf16(af, bv, acc[j], 0, 0, 0);
            }
            __syncthreads();
        }
        const int m = w * 16;
#pragma unroll
        for (int j = 0; j < 4; ++j)
#pragma unroll
            for (int r = 0; r < 4; ++r)
                fproj[(size_t)(r0 + m + g * 4 + r) * HH + n0 + j * 16 + c] = (f16)acc[j][r];
    } else if (blk < 328) {
        // Wo -> fp8, swizzled layout. Per 64-k chunk: 2 subplanes x 4 g-planes
        // x 144 slots (16B each). Logical slot = s*576 + g*144 + p*16 + c:
        //   p=0..7: pair slot {j=2p, j=2p+1} for col class c (cols j*16+c)
        //   p=8   : tail slot, long0 = col 256+c (only c=0 real), long1 = pad
        // Stored slot = (row<<3) | ((slot&7) ^ (row&7)), row = slot>>3.
        // This spreads the consumer's b128 reads across bank quads (2-way max).
        int idx = (blk - 256) * 256 + tid;  // 0..18431 (dest long index)
        int chunk = idx / BLONGS;
        int wi = idx - chunk * BLONGS;
        int slot_sw = wi >> 1;
        int lo = wi & 1;
        int row = slot_sw >> 3;
        int quad = (slot_sw & 7) ^ (row & 7);  // invert involution -> logical
        int slot_log = (row << 3) | quad;
        int s = slot_log / 576;
        int r1 = slot_log - s * 576;
        int g = r1 / 144;
        int r2 = r1 - g * 144;
        int p = r2 >> 4;
        int cc = r2 & 15;
        int n = (p == 8) ? ((lo == 0) ? 256 + cc : NV)
                         : (2 * p + lo) * 16 + cc;
        float v[8];
#pragma unroll
        for (int e = 0; e < 8; ++e) {
            int k = chunk * 64 + s * 32 + g * 8 + e;
            v[e] = (n < NV) ? Wo[k * NV + n] * WOSCL : 0.f;
        }
        Wo_s[idx] = pack_fp8x8(v);
    } else {
        int u = blk - 328;  // 0..96
        for (int b = 0; b < BB; ++b) {
            int ctx = (u == 0) ? 0 : labels[b * UU + (u - 1)];
            const float* src = E + (size_t)ctx * HH;
            f16* dst = cemb + ((size_t)b * NU + u) * HH;
            for (int i = tid; i < HH; i += 256) dst[i] = (f16)src[i];
        }
    }
}

// ---- joint: logits = tanh(fproj[t]+cemb[u]) @ Wo  [fp8 MFMA, BK=64 K-loop]
// grid (776, B), block 256 = 4 waves = 4 M-slots of 16 rows; each wave owns
// 16 rows x 272 cols (acc[17] f32x4). A-fragments in registers: lane
// (c=lane&15, g=lane>>4) tanh-packs row (w*16+c), k-octet g directly into
// the MFMA A operand. B double-buffered via global_load_lds, read as
// swizzled b128 pairs (9 precomputed loop-invariant addresses). One barrier
// per 64-k chunk. Base-2 epilogue, 16B cl store.
__global__ __launch_bounds__(256, 4) void k_joint(
    const f16* __restrict__ fproj, const f16* __restrict__ cemb,
    const long* __restrict__ Wo_s, const int* __restrict__ labels,
    const int* __restrict__ num_frames, f16* __restrict__ cl_arr) {
    __shared__ __align__(16) long B_s8[2][BLONGS];  // 2 x 18432 B

    const int tid = threadIdx.x;
    const int b = blockIdx.y;
    const int r0 = blockIdx.x * 64;
    const int nf = num_frames[b];
    if (r0 / NU >= nf) return;  // whole tile beyond active frames: outputs unused

    const int lane = tid & 63, w = tid >> 6;
    const int c = lane & 15, g = lane >> 4;

    // This lane's A row and k-octet: row = w*16 + c, k = g*8 + s*32 + i*64.
    const int gr = r0 + w * 16 + c;
    const int at = gr / NU, au = gr - at * NU;
    const f16* pf = fproj + ((size_t)(b * TT + at)) * HH + g * 8;
    const f16* pc = cemb + ((size_t)(b * NU + au)) * HH + g * 8;
    const char* wsrcB = (const char*)Wo_s + lane * 16;

    f32x4 acc[17];
#pragma unroll
    for (int j = 0; j < 17; ++j) acc[j] = (f32x4){0.f, 0.f, 0.f, 0.f};

    // Swizzled B read addresses (long index within a chunk buffer), s=0.
    // logical slot = g*144 + p*16 + c  ->  row = 18g + (c>>3) + 2p,
    // stored quad = (c&7) ^ (row&7).  s=1 adds 1152 longs (row&7 invariant).
    const int hb = c >> 3, cq = c & 7;
    int addr[9];
#pragma unroll
    for (int p = 0; p < 8; ++p) {
        int row = g * 18 + hb + 2 * p;
        addr[p] = (((row << 3) | (cq ^ (row & 7))) << 1);
    }
    {
        int row = g * 18 + 16 + hb;  // tail slot p=8
        addr[8] = (((row << 3) | (cq ^ (row & 7))) << 1);
    }

    long a0, a1;  // current chunk A-frags (s=0: k..k+31, s=1: k+32..k+63)

    // ---- prologue: stage B chunk 0, compute A-frags for chunk 0 ----
    {
        for (int ch = w; ch < 18; ch += 4)
            async_copy16(wsrcB + ch * 1024, (char*)&B_s8[0][0] + ch * 1024 + lane * 16);
        f16x8 fv0 = *(const f16x8*)pf;
        f16x8 cv0 = *(const f16x8*)pc;
        f16x8 fv1 = *(const f16x8*)(pf + 32);
        f16x8 cv1 = *(const f16x8*)(pc + 32);
        a0 = tanh_pack8(fv0, cv0);
        a1 = tanh_pack8(fv1, cv1);
        __syncthreads();
    }

    // ---- main loop: one barrier per 64-k chunk ----
    for (int i = 0; i < 8; ++i) {
        const int cur = i & 1, nxt = cur ^ 1;
        f16x8 fv0, cv0, fv1, cv1;
        // B async + A loads for i+1 FIRST: fly through the s=0 MFMA cluster
        if (i < 7) {
            const char* wk = wsrcB + (size_t)(i + 1) * BCHUNK;
            for (int ch = w; ch < 18; ch += 4)
                async_copy16(wk + ch * 1024, (char*)&B_s8[nxt][0] + ch * 1024 + lane * 16);
            const int kt = (i + 1) * 64;
            fv0 = *(const f16x8*)(pf + kt);
            cv0 = *(const f16x8*)(pc + kt);
            fv1 = *(const f16x8*)(pf + kt + 32);
            cv1 = *(const f16x8*)(pc + kt + 32);
        }
        __builtin_amdgcn_s_setprio(1);
#pragma unroll
        for (int p = 0; p < 8; ++p) {
            longx2 bv = *(const longx2*)&B_s8[cur][addr[p]];
            acc[2 * p] = __builtin_amdgcn_mfma_f32_16x16x32_fp8_fp8(a0, bv[0], acc[2 * p], 0, 0, 0);
            acc[2 * p + 1] = __builtin_amdgcn_mfma_f32_16x16x32_fp8_fp8(a0, bv[1], acc[2 * p + 1], 0, 0, 0);
        }
        acc[16] = __builtin_amdgcn_mfma_f32_16x16x32_fp8_fp8(a0, B_s8[cur][addr[8]], acc[16], 0, 0, 0);
        __builtin_amdgcn_s_setprio(0);
        // tanh between the clusters: loads had the whole s=0 cluster to land;
        // only 4 regs (a0n,a1n) stay live across the s=1 cluster.
        long a0n, a1n;
        if (i < 7) {
            a0n = tanh_pack8(fv0, cv0);
            a1n = tanh_pack8(fv1, cv1);
        }
        __builtin_amdgcn_s_setprio(1);
#pragma unroll
        for (int p = 0; p < 8; ++p) {
            longx2 bv = *(const longx2*)&B_s8[cur][addr[p] + 1152];
            acc[2 * p] = __builtin_amdgcn_mfma_f32_16x16x32_fp8_fp8(a1, bv[0], acc[2 * p], 0, 0, 0);
            acc[2 * p + 1] = __builtin_amdgcn_mfma_f32_16x16x32_fp8_fp8(a1, bv[1], acc[2 * p + 1], 0, 0, 0);
        }
        acc[16] = __builtin_amdgcn_mfma_f32_16x16x32_fp8_fp8(a1, B_s8[cur][addr[8] + 1152], acc[16], 0, 0, 0);
        __builtin_amdgcn_s_setprio(0);
        if (i < 7) {
            a0 = a0n;
            a1 = a1n;
            __syncthreads();
        }
    }

    // epilogue: wave owns 16 complete rows -> fully in-wave LSE, base-2.
    // acc is in the x64 pre-scaled domain; fold descale+base2 into one fma:
    // p = exp2(acc*C2 - mx*C2), lse2 = mx*C2 + log2(sum). cl stored base-2.
    const int rbase = r0 + w * 16 + g * 4;
    f16x8 ovs;
#pragma unroll
    for (int r = 0; r < 4; ++r) {
        const int grr = rbase + r;
        const int u = grr - (grr / NU) * NU;

        float mx = NEG_INF;
#pragma unroll
        for (int j = 0; j < 17; ++j) {
            int col = j * 16 + c;
            if (col < NV) mx = fmaxf(mx, acc[j][r]);
        }
#pragma unroll
        for (int s = 1; s < 16; s <<= 1) mx = fmaxf(mx, __shfl_xor(mx, s));
        float mxc = mx * C2SCL;
        float sum = 0.f;
#pragma unroll
        for (int j = 0; j < 17; ++j) {
            int col = j * 16 + c;
            if (col < NV)
                sum += __builtin_amdgcn_exp2f(fmaf(acc[j][r], C2SCL, -mxc));
        }
#pragma unroll
        for (int s = 1; s < 16; s <<= 1) sum += __shfl_xor(sum, s);
        float lse2 = mxc + __builtin_amdgcn_logf(sum);

        float blankv = __shfl(acc[0][r], lane & 48);  // col 0 (raw domain)
        int L = (u < UU) ? labels[b * UU + u] : 0;    // 1..256 (or dummy 0)
        int jl = L >> 4;
        float v = acc[0][r];
#pragma unroll
        for (int j = 1; j < 17; ++j)
            if (jl == j) v = acc[j][r];               // static-index select
        float lexv = __shfl(v, (lane & 48) | (L & 15));

        ovs[2 * r] = (f16)fmaf(blankv, C2SCL, -lse2);
        ovs[2 * r + 1] = (u < UU) ? (f16)fmaf(lexv, C2SCL, -lse2) : (f16)0.f;
    }
    // rows rbase..rbase+3 are contiguous in flat (t*NU+u) -> one 16B store.
    if (c == 0)
        *(f16x8*)&cl_arr[((size_t)b * TT * NU + rbase) * 2] = ovs;
}

// ---- parallel depth-4 compaction: grid (NG, BB), block 128 (one thread per u).
__global__ __launch_bounds__(128) void k_compact(
    const f16* __restrict__ cl, const int* __restrict__ num_frames,
    float* __restrict__ Dg) {
    const int g = blockIdx.x;
    const int b = blockIdx.y;
    const int u = threadIdx.x;
    if (u >= NU) return;
    const int nf = num_frames[b];
    const f16x2* P = (const f16x2*)(cl + (size_t)b * TT * NU * 2);

    auto fetch = [&](int t, int uu, float& bb, float& ll) {
        if (uu <= UU) {
            f16x2 z = P[t * NU + uu];
            bool act = t < nf;
            bb = act ? (float)z.x : 0.f;                      // already base-2
            ll = (act && uu < UU) ? (float)z.y : NEG_INF;
        } else {
            bb = NEG_INF;
            ll = NEG_INF;
        }
    };

    const int t0 = g * 4;
    float b0, l0, b1u, l1u, b1u1, l1u1;
    fetch(t0, u, b0, l0);
    fetch(t0 + 1, u, b1u, l1u);
    fetch(t0 + 1, u + 1, b1u1, l1u1);
    float A0 = b0 + b1u;
    float A1 = lae2(l0 + b1u1, b0 + l1u);
    float A2 = l0 + l1u1;
    float B0[3], B1[3], B2[3];
#pragma unroll
    for (int j = 0; j < 3; ++j) {
        float b2v, l2v, b3v, l3v, b3n, l3n;
        fetch(t0 + 2, u + j, b2v, l2v);
        fetch(t0 + 3, u + j, b3v, l3v);
        fetch(t0 + 3, u + j + 1, b3n, l3n);
        B0[j] = b2v + b3v;
        B1[j] = lae2(l2v + b3n, b2v + l3v);
        B2[j] = l2v + l3n;
    }
    float* d = Dg + ((size_t)b * NG + g) * GSTRIDE;
    d[u] = A0 + B0[0];
    d[104 + u] = lae2(A1 + B0[1], A0 + B1[0]);
    d[208 + u] = lse3_2(A2 + B0[2], A1 + B1[1], A0 + B2[0]);
    d[312 + u] = lae2(A2 + B1[2], A1 + B2[1]);
    d[416 + u] = A2 + B2[2];
}

// ---- serial chain: 1 wave per batch, 128 banded-lse5 steps.
// Dg staged through LDS (8-group chunks, triple-buffered, counted vmcnt);
// register ring (depth 4) refills from LDS. No HBM on the serial path.
__global__ __launch_bounds__(64) void k_dpser(
    const float* __restrict__ Dg, const int* __restrict__ num_labels,
    float* __restrict__ out) {
    __shared__ __align__(16) float Dl[3 * CHF];  // 3 x 20480B = 61440B
    const int b = blockIdx.x;
    const int lane = threadIdx.x;
    const char* Db = (const char*)(Dg + (size_t)b * NG * GSTRIDE);
    const int lo_u = lane;
    const int hi_u = 64 + ((lane < 33) ? lane : 0);

    // stage chunk q (groups q*8 .. q*8+7) into LDS buffer q%3
    auto stage = [&](int q) {
        const char* src = Db + (size_t)q * CHB + lane * 16;
        char* dst = (char*)Dl + (q % 3) * CHB + lane * 16;
#pragma unroll
        for (int i = 0; i < CHI; ++i)
            async_copy16(src + i * 1024, dst + i * 1024);
    };

    stage(0);
    stage(1);
    asm volatile("s_waitcnt vmcnt(20)" ::: "memory");  // chunk 0 landed

    float a_lo = (lane == 0) ? 0.f : NEG_INF;  // alpha[u=lane] (base-2)
    float a_hi = NEG_INF;                      // alpha[u=64+lane], lane<33

    constexpr int R = 4;
    float blo[R][5], bhi[R][5];
    // ring prologue: groups 0..3 (chunk 0, buffer 0)
#pragma unroll
    for (int g = 0; g < R; ++g)
#pragma unroll
        for (int k = 0; k < 5; ++k) {
            blo[g][k] = Dl[g * GSTRIDE + k * 104 + lo_u];
            bhi[g][k] = Dl[g * GSTRIDE + k * 104 + hi_u];
        }

    int bc = 0;      // float offset of buffer holding chunk c
    int bn = CHF;    // buffer of chunk c+1
    for (int c = 0; c < NG / CHG; ++c) {
        // issue chunk c+2 into buffer (c+2)%3 (not read since chunk c-1's
        // compute; all its ds_reads retired), then prove chunk c+1 landed.
        if (c + 2 < NG / CHG) {
            stage(c + 2);
            asm volatile("s_waitcnt vmcnt(20)" ::: "memory");
        } else {
            asm volatile("s_waitcnt vmcnt(0)" ::: "memory");
        }
#pragma unroll
        for (int g8 = 0; g8 < CHG; ++g8) {
            const int slot = g8 & 3;
            float el[5], eh[5];
#pragma unroll
            for (int k = 0; k < 5; ++k) {
                el[k] = a_lo + blo[slot][k];
                eh[k] = a_hi + bhi[slot][k];
            }
            // refill slot with group g+4 from LDS (chunk c for g8<4, else c+1)
            const int g = c * CHG + g8;
            if (g + 4 < NG) {
                const int rb = (g8 < 4) ? bc : bn;
                const int rs = (g8 + 4) & 7;
#pragma unroll
                for (int k = 0; k < 5; ++k) {
                    blo[slot][k] = Dl[rb + rs * GSTRIDE + k * 104 + lo_u];
                    bhi[slot][k] = Dl[rb + rs * GSTRIDE + k * 104 + hi_u];
                }
            }
            float ml[5], mh[5];
            ml[0] = el[0];
            mh[0] = eh[0];
#pragma unroll
            for (int k = 1; k < 5; ++k) {
                float su = __shfl_up(el[k], k);
                ml[k] = (lane >= k) ? su : NEG_INF;
                float sh = __shfl_up(eh[k], k);
                float xl = __shfl(el[k], 64 - k + lane);  // lo lanes 63..64-k
                mh[k] = (lane >= k) ? sh : xl;
            }
            a_lo = lse5_2(ml[0], ml[1], ml[2], ml[3], ml[4]);
            float nh = lse5_2(mh[0], mh[1], mh[2], mh[3], mh[4]);
            if (lane < 33) a_hi = nh;
        }
        bc = bn;
        bn = (bn == 2 * CHF) ? 0 : bn + CHF;
    }

    const int nl = num_labels[b];
    float res = (nl < 64) ? __shfl(a_lo, nl) : __shfl(a_hi, nl - 64);
    if (lane == 0) out[b] = -res * LN2;  // back to natural-log domain
}

extern "C" void kernel_launch(void* const* d_in, const int* in_sizes, int n_in,
                              void* d_out, int out_size, void* d_ws, size_t ws_size,
                              hipStream_t stream) {
    const float* frames = (const float*)d_in[0];
    const int* num_frames = (const int*)d_in[1];
    const int* labels = (const int*)d_in[2];
    const int* num_labels = (const int*)d_in[3];
    const float* Wf = (const float*)d_in[4];
    const float* E = (const float*)d_in[5];
    const float* Wo = (const float*)d_in[6];
    float* out = (float*)d_out;

    char* ws = (char*)d_ws;
    size_t off = 0;
    long* Wo_s = (long*)(ws + off); off += (size_t)18432 * 8;                 // 144 KiB
    f16* cemb = (f16*)(ws + off); off += (size_t)BB * NU * HH * 2;            // 388 KiB
    off = (off + 255) & ~(size_t)255;
    f16* fproj = (f16*)(ws + off); off += (size_t)BB * TT * HH * 2;           // 2 MiB
    off = (off + 255) & ~(size_t)255;
    f16* cl_arr = (f16*)(ws + off); off += (size_t)BB * TT * NU * 2 * 2;      // 776 KiB
    off = (off + 255) & ~(size_t)255;
    float* Dg = (float*)(ws + off); off += (size_t)BB * NG * GSTRIDE * 4;     // 1.31 MiB

    hipLaunchKernelGGL(k_front, dim3(425), dim3(256), 0, stream,
                       frames, Wf, Wo, E, labels, fproj, Wo_s, cemb);
    hipLaunchKernelGGL(k_joint, dim3((TT * NU) / 64, BB), dim3(256), 0, stream,
                       fproj, cemb, Wo_s, labels, num_frames, cl_arr);
    hipLaunchKernelGGL(k_compact, dim3(NG, BB), dim3(128), 0, stream,
                       cl_arr, num_frames, Dg);
    hipLaunchKernelGGL(k_dpser, dim3(BB), dim3(64), 0, stream,
                       Dg, num_labels, out);
}

// Round 9
// 168.595 us; speedup vs baseline: 1.1703x; 1.1703x over previous
//
#include <hip/hip_runtime.h>
#include <hip/hip_bf16.h>

// RecognitionLattice: RNN-T style lattice loss.
// k_front: fproj GEMM (direct fp32-Wf transpose staging, f16 out) + Wo->fp8
//          shuffle (NP=272, PAIRED col layout for b128 LDS reads) + cemb (f16)
// -> k_joint: h=tanh(fproj+cemb) packed-f16 -> fp8 @ Wo_fp8, BK=64 K-loop.
//    4-wave blocks (64-row tiles), A-frags in registers, B double-buffered
//    via global_load_lds (b128 pairs), base-2 epilogue, 16B cl store.
//    (r6-exact: sits at the 128-VGPR cliff; r8's swizzle spilled -> reverted)
// -> k_compact: depth-4 semiring compaction x2 + in-LDS pairwise composition
//    -> depth-8 operators (9 bands), halving the serial chain length.
// -> k_dpser: 1 wave/batch serial chain, 64 banded-lse9 steps. Dg staged
//    through LDS in 4-group chunks (15 x 1KiB async copies), QUAD-buffered
//    with counted vmcnt(30) -> >=2 chunk-computes of prefetch flight.

#define BB 4
#define TT 512
#define UU 96
#define FF 512
#define HH 512
#define VV 256
#define NV (VV + 1)    // 257 vocab incl. blank
#define NU 97          // lattice rows per t
#define NP 272         // 17*16 padded N (257 -> 272)
#define NEG_INF (-1e30f)
#define LN2 0.6931471805599453f
#define WOSCL 64.0f    // Wo pre-scale into fp8 normal range
#define C2SCL 0.022542110f  // log2(e)/64: descale+base2 fold for the LSE
#define BCHUNK 17408   // bytes per 64-k B chunk = 64*272 fp8
#define BLONGS 2176    // longs per chunk
#define SPLANE 1088    // longs per 32-k sub-plane
// depth-8 operator bank
#define NG2 64         // groups of 8 t-steps
#define GS2 960        // padded floats per depth-8 operator (936 used)
#define CH2G 4                     // dpser: groups per staged chunk
#define CH2B (CH2G * GS2 * 4)      // 15360 bytes per chunk
#define CH2I (CH2B / 1024)         // 15 async copies per chunk
#define CH2F (CH2G * GS2)          // floats per chunk buffer
#define NCH 16                     // chunks

typedef _Float16 f16;
typedef __attribute__((ext_vector_type(2))) _Float16 f16x2;
typedef __attribute__((ext_vector_type(8))) _Float16 f16x8;
typedef __attribute__((ext_vector_type(2))) long longx2;
typedef __bf16 bf16;
typedef __bf16 bf16x8 __attribute__((ext_vector_type(8)));
typedef float f32x4 __attribute__((ext_vector_type(4)));

__device__ __forceinline__ f16x8 splat8(float s) {
    f16 v = (f16)s;
    f16x8 r = {v, v, v, v, v, v, v, v};
    return r;
}

// tanh via clamped odd polynomial in PACKED f16 (v_pk_* dual-issue), then
// fp8 e4m3 pack. Max poly err ~0.007 on [-2,2]; f16 intermediate err ~1e-3
// << fp8 output quantization.
__device__ __forceinline__ long tanh_pack8(f16x8 fv8, f16x8 cv8) {
    f16x8 x = fv8 + cv8;
    x = __builtin_elementwise_min(__builtin_elementwise_max(x, splat8(-2.0f)),
                                  splat8(2.0f));
    f16x8 y = x * x;
    f16x8 q = y * splat8(-0.0067528f) + splat8(0.0700672f);
    q = y * q + splat8(-0.301720f);
    q = y * q + splat8(1.0f);
    f16x8 t = x * q;
    int lo = 0, hi = 0;
    lo = __builtin_amdgcn_cvt_pk_fp8_f32((float)t[0], (float)t[1], lo, false);
    lo = __builtin_amdgcn_cvt_pk_fp8_f32((float)t[2], (float)t[3], lo, true);
    hi = __builtin_amdgcn_cvt_pk_fp8_f32((float)t[4], (float)t[5], hi, false);
    hi = __builtin_amdgcn_cvt_pk_fp8_f32((float)t[6], (float)t[7], hi, true);
    return (long)(((unsigned long long)(unsigned int)lo) |
                  (((unsigned long long)(unsigned int)hi) << 32));
}

// pack 8 floats -> 8 fp8 e4m3 (for Wo prep)
__device__ __forceinline__ long pack_fp8x8(const float* v) {
    int lo = 0, hi = 0;
    lo = __builtin_amdgcn_cvt_pk_fp8_f32(v[0], v[1], lo, false);
    lo = __builtin_amdgcn_cvt_pk_fp8_f32(v[2], v[3], lo, true);
    hi = __builtin_amdgcn_cvt_pk_fp8_f32(v[4], v[5], hi, false);
    hi = __builtin_amdgcn_cvt_pk_fp8_f32(v[6], v[7], hi, true);
    return (long)(((unsigned long long)(unsigned int)lo) |
                  (((unsigned long long)(unsigned int)hi) << 32));
}

// base-2 log-domain ops
__device__ __forceinline__ float lae2(float x, float y) {
    float m = fmaxf(x, y);
    float d = fminf(x, y) - m;
    return m + __builtin_amdgcn_logf(1.0f + __builtin_amdgcn_exp2f(d));
}

__device__ __forceinline__ float lse3_2(float x, float y, float z) {
    float m = fmaxf(fmaxf(x, y), z);
    float s = __builtin_amdgcn_exp2f(x - m) + __builtin_amdgcn_exp2f(y - m) +
              __builtin_amdgcn_exp2f(z - m);
    return m + __builtin_amdgcn_logf(s);
}

__device__ __forceinline__ float lse5_2(float a, float b, float c, float d, float e) {
    float m = fmaxf(fmaxf(fmaxf(a, b), fmaxf(c, d)), e);
    float s = __builtin_amdgcn_exp2f(a - m) + __builtin_amdgcn_exp2f(b - m) +
              __builtin_amdgcn_exp2f(c - m) + __builtin_amdgcn_exp2f(d - m) +
              __builtin_amdgcn_exp2f(e - m);
    return m + __builtin_amdgcn_logf(s);
}

__device__ __forceinline__ float lse9_2(const float* v) {
    float m1 = fmaxf(fmaxf(v[0], v[1]), v[2]);
    float m2 = fmaxf(fmaxf(v[3], v[4]), v[5]);
    float m3 = fmaxf(fmaxf(v[6], v[7]), v[8]);
    float m = fmaxf(fmaxf(m1, m2), m3);
    float s = 0.f;
#pragma unroll
    for (int k = 0; k < 9; ++k) s += __builtin_amdgcn_exp2f(v[k] - m);
    return m + __builtin_amdgcn_logf(s);
}

__device__ __forceinline__ void async_copy16(const void* g, void* l) {
    __builtin_amdgcn_global_load_lds(
        (const __attribute__((address_space(1))) unsigned int*)g,
        (__attribute__((address_space(3))) unsigned int*)l, 16, 0, 0);
}

// ---- front: fproj GEMM + Wo->fp8 shuffle + cemb gather
__global__ __launch_bounds__(256, 2) void k_front(
    const float* __restrict__ frames, const float* __restrict__ Wf,
    const float* __restrict__ Wo, const float* __restrict__ E,
    const int* __restrict__ labels, f16* __restrict__ fproj,
    long* __restrict__ Wo_s, f16* __restrict__ cemb) {
    __shared__ bf16 Alds[64 * 40];
    __shared__ bf16 Blds[64 * 40];
    const int blk = blockIdx.x;
    const int tid = threadIdx.x;

    if (blk < 256) {
        const int r0 = (blk & 31) * 64;
        const int n0 = (blk >> 5) * 64;
        const int lane = tid & 63, w = tid >> 6;
        const int c = lane & 15, g = lane >> 4;

        const int srow = tid >> 2, sko = (tid & 3) * 8;
        const float* fptr = frames + (size_t)(r0 + srow) * FF + sko;
        const int q = tid >> 6, c64 = tid & 63;  // B-transpose staging coords

        f32x4 acc[4];
#pragma unroll
        for (int j = 0; j < 4; ++j) acc[j] = (f32x4){0.f, 0.f, 0.f, 0.f};

        for (int kt = 0; kt < FF; kt += 32) {
            float4 f1 = *(const float4*)(fptr + kt);
            float4 f2 = *(const float4*)(fptr + kt + 4);
            bf16x8 av = {(bf16)f1.x, (bf16)f1.y, (bf16)f1.z, (bf16)f1.w,
                         (bf16)f2.x, (bf16)f2.y, (bf16)f2.z, (bf16)f2.w};
            *(bf16x8*)&Alds[srow * 40 + sko] = av;
#pragma unroll
            for (int p = 0; p < 8; ++p) {
                float v = Wf[(size_t)(kt + q * 8 + p) * HH + n0 + c64];
                Blds[c64 * 40 + q * 8 + p] = (bf16)v;
            }
            __syncthreads();
            const int m = w * 16;
            bf16x8 af = *(const bf16x8*)&Alds[(m + c) * 40 + g * 8];
#pragma unroll
            for (int j = 0; j < 4; ++j) {
                bf16x8 bv = *(const bf16x8*)&Blds[(j * 16 + c) * 40 + g * 8];
                acc[j] = __builtin_amdgcn_mfma_f32_16x16x32_bf16(af, bv, acc[j], 0, 0, 0);
            }
            __syncthreads();
        }
        const int m = w * 16;
#pragma unroll
        for (int j = 0; j < 4; ++j)
#pragma unroll
            for (int r = 0; r < 4; ++r)
                fproj[(size_t)(r0 + m + g * 4 + r) * HH + n0 + j * 16 + c] = (f16)acc[j][r];
    } else if (blk < 324) {
        // Wo -> fp8, PAIRED layout: within plane (k32,g), position
        //   pos = (j>>1)*32 + c*2 + (j&1)  for j=0..15 (cols j*16+c)
        //   pos = 256 + c                  for j=16    (cols 256+c)
        // so k_joint reads (2p,2p+1) as one ds_read_b128 per lane.
        int idx = (blk - 256) * 256 + tid;  // 0..17407
        int pos = idx % NP;
        int plane = idx / NP;
        int g = plane & 3;
        int k32 = plane >> 2;
        int n;
        if (pos < 256) {
            int j = ((pos >> 5) << 1) | (pos & 1);
            int cc = (pos >> 1) & 15;
            n = j * 16 + cc;
        } else {
            n = 256 + (pos - 256);
        }
        float v[8];
#pragma unroll
        for (int e = 0; e < 8; ++e) {
            int k = k32 * 32 + g * 8 + e;
            v[e] = (n < NV) ? Wo[k * NV + n] * WOSCL : 0.f;
        }
        Wo_s[idx] = pack_fp8x8(v);
    } else {
        int u = blk - 324;  // 0..96
        for (int b = 0; b < BB; ++b) {
            int ctx = (u == 0) ? 0 : labels[b * UU + (u - 1)];
            const float* src = E + (size_t)ctx * HH;
            f16* dst = cemb + ((size_t)b * NU + u) * HH;
            for (int i = tid; i < HH; i += 256) dst[i] = (f16)src[i];
        }
    }
}

// ---- joint: logits = tanh(fproj[t]+cemb[u]) @ Wo  [fp8 MFMA, BK=64 K-loop]
// r6-exact. grid (776, B), block 256 = 4 waves = 4 M-slots of 16 rows.
__global__ __launch_bounds__(256, 4) void k_joint(
    const f16* __restrict__ fproj, const f16* __restrict__ cemb,
    const long* __restrict__ Wo_s, const int* __restrict__ labels,
    const int* __restrict__ num_frames, f16* __restrict__ cl_arr) {
    __shared__ __align__(16) long B_s8[2][BLONGS];  // 2 x 17408 B

    const int tid = threadIdx.x;
    const int b = blockIdx.y;
    const int r0 = blockIdx.x * 64;
    const int nf = num_frames[b];
    if (r0 / NU >= nf) return;  // whole tile beyond active frames: outputs unused

    const int lane = tid & 63, w = tid >> 6;
    const int c = lane & 15, g = lane >> 4;

    const int gr = r0 + w * 16 + c;
    const int at = gr / NU, au = gr - at * NU;
    const f16* pf = fproj + ((size_t)(b * TT + at)) * HH + g * 8;
    const f16* pc = cemb + ((size_t)(b * NU + au)) * HH + g * 8;
    const char* wsrcB = (const char*)Wo_s + lane * 16;

    f32x4 acc[17];
#pragma unroll
    for (int j = 0; j < 17; ++j) acc[j] = (f32x4){0.f, 0.f, 0.f, 0.f};

    const int bB0p = g * NP + (c << 1);   // paired-B base (longs)
    const int bB16 = g * NP + 256 + c;    // j=16 tail (longs)

    long a0, a1;  // current chunk A-frags

    // ---- prologue: stage B chunk 0, compute A-frags for chunk 0 ----
    {
        for (int ch = w; ch < 17; ch += 4)
            async_copy16(wsrcB + ch * 1024, (char*)&B_s8[0][0] + ch * 1024 + lane * 16);
        f16x8 fv0 = *(const f16x8*)pf;
        f16x8 cv0 = *(const f16x8*)pc;
        f16x8 fv1 = *(const f16x8*)(pf + 32);
        f16x8 cv1 = *(const f16x8*)(pc + 32);
        a0 = tanh_pack8(fv0, cv0);
        a1 = tanh_pack8(fv1, cv1);
        __syncthreads();
    }

    // ---- main loop: one barrier per 64-k chunk ----
    for (int i = 0; i < 8; ++i) {
        const int cur = i & 1, nxt = cur ^ 1;
        f16x8 fv0, cv0, fv1, cv1;
        if (i < 7) {
            const char* wk = wsrcB + (size_t)(i + 1) * BCHUNK;
            for (int ch = w; ch < 17; ch += 4)
                async_copy16(wk + ch * 1024, (char*)&B_s8[nxt][0] + ch * 1024 + lane * 16);
            const int kt = (i + 1) * 64;
            fv0 = *(const f16x8*)(pf + kt);
            cv0 = *(const f16x8*)(pc + kt);
            fv1 = *(const f16x8*)(pf + kt + 32);
            cv1 = *(const f16x8*)(pc + kt + 32);
        }
        __builtin_amdgcn_s_setprio(1);
#pragma unroll
        for (int p = 0; p < 8; ++p) {
            longx2 bv = *(const longx2*)&B_s8[cur][bB0p + p * 32];
            acc[2 * p] = __builtin_amdgcn_mfma_f32_16x16x32_fp8_fp8(a0, bv[0], acc[2 * p], 0, 0, 0);
            acc[2 * p + 1] = __builtin_amdgcn_mfma_f32_16x16x32_fp8_fp8(a0, bv[1], acc[2 * p + 1], 0, 0, 0);
        }
        acc[16] = __builtin_amdgcn_mfma_f32_16x16x32_fp8_fp8(a0, B_s8[cur][bB16], acc[16], 0, 0, 0);
        __builtin_amdgcn_s_setprio(0);
        long a0n, a1n;
        if (i < 7) {
            a0n = tanh_pack8(fv0, cv0);
            a1n = tanh_pack8(fv1, cv1);
        }
        __builtin_amdgcn_s_setprio(1);
#pragma unroll
        for (int p = 0; p < 8; ++p) {
            longx2 bv = *(const longx2*)&B_s8[cur][SPLANE + bB0p + p * 32];
            acc[2 * p] = __builtin_amdgcn_mfma_f32_16x16x32_fp8_fp8(a1, bv[0], acc[2 * p], 0, 0, 0);
            acc[2 * p + 1] = __builtin_amdgcn_mfma_f32_16x16x32_fp8_fp8(a1, bv[1], acc[2 * p + 1], 0, 0, 0);
        }
        acc[16] = __builtin_amdgcn_mfma_f32_16x16x32_fp8_fp8(a1, B_s8[cur][SPLANE + bB16], acc[16], 0, 0, 0);
        __builtin_amdgcn_s_setprio(0);
        if (i < 7) {
            a0 = a0n;
            a1 = a1n;
            __syncthreads();
        }
    }

    // epilogue: wave owns 16 complete rows -> fully in-wave LSE, base-2.
    const int rbase = r0 + w * 16 + g * 4;
    f16x8 ovs;
#pragma unroll
    for (int r = 0; r < 4; ++r) {
        const int grr = rbase + r;
        const int u = grr - (grr / NU) * NU;

        float mx = NEG_INF;
#pragma unroll
        for (int j = 0; j < 17; ++j) {
            int col = j * 16 + c;
            if (col < NV) mx = fmaxf(mx, acc[j][r]);
        }
#pragma unroll
        for (int s = 1; s < 16; s <<= 1) mx = fmaxf(mx, __shfl_xor(mx, s));
        float mxc = mx * C2SCL;
        float sum = 0.f;
#pragma unroll
        for (int j = 0; j < 17; ++j) {
            int col = j * 16 + c;
            if (col < NV)
                sum += __builtin_amdgcn_exp2f(fmaf(acc[j][r], C2SCL, -mxc));
        }
#pragma unroll
        for (int s = 1; s < 16; s <<= 1) sum += __shfl_xor(sum, s);
        float lse2 = mxc + __builtin_amdgcn_logf(sum);

        float blankv = __shfl(acc[0][r], lane & 48);  // col 0 (raw domain)
        int L = (u < UU) ? labels[b * UU + u] : 0;    // 1..256 (or dummy 0)
        int jl = L >> 4;
        float v = acc[0][r];
#pragma unroll
        for (int j = 1; j < 17; ++j)
            if (jl == j) v = acc[j][r];               // static-index select
        float lexv = __shfl(v, (lane & 48) | (L & 15));

        ovs[2 * r] = (f16)fmaf(blankv, C2SCL, -lse2);
        ovs[2 * r + 1] = (u < UU) ? (f16)fmaf(lexv, C2SCL, -lse2) : (f16)0.f;
    }
    if (c == 0)
        *(f16x8*)&cl_arr[((size_t)b * TT * NU + rbase) * 2] = ovs;
}

// ---- depth-8 compaction: grid (NG2, BB), block 128 (one thread per u).
// Two depth-4 operators composed in LDS -> 9-band depth-8 operator.
__global__ __launch_bounds__(128) void k_compact(
    const f16* __restrict__ cl, const int* __restrict__ num_frames,
    float* __restrict__ Dg) {
    __shared__ float Bl[5][128];
    const int g = blockIdx.x;   // 0..63 (8-frame group)
    const int b = blockIdx.y;
    const int u = threadIdx.x;  // 0..127
    const int nf = num_frames[b];
    const f16x2* P = (const f16x2*)(cl + (size_t)b * TT * NU * 2);

    auto fetch = [&](int t, int uu, float& bb, float& ll) {
        if (uu <= UU) {
            f16x2 z = P[t * NU + uu];
            bool act = t < nf;
            bb = act ? (float)z.x : 0.f;                      // base-2 already
            ll = (act && uu < UU) ? (float)z.y : NEG_INF;
        } else {
            bb = NEG_INF;
            ll = NEG_INF;
        }
    };

    auto depth4 = [&](int t0, float* D) {
        float b0, l0, b1u, l1u, b1u1, l1u1;
        fetch(t0, u, b0, l0);
        fetch(t0 + 1, u, b1u, l1u);
        fetch(t0 + 1, u + 1, b1u1, l1u1);
        float A0 = b0 + b1u;
        float A1 = lae2(l0 + b1u1, b0 + l1u);
        float A2 = l0 + l1u1;
        float B0[3], B1[3], B2[3];
#pragma unroll
        for (int j = 0; j < 3; ++j) {
            float b2v, l2v, b3v, l3v, b3n, l3n;
            fetch(t0 + 2, u + j, b2v, l2v);
            fetch(t0 + 3, u + j, b3v, l3v);
            fetch(t0 + 3, u + j + 1, b3n, l3n);
            B0[j] = b2v + b3v;
            B1[j] = lae2(l2v + b3n, b2v + l3v);
            B2[j] = l2v + l3n;
        }
        D[0] = A0 + B0[0];
        D[1] = lae2(A1 + B0[1], A0 + B1[0]);
        D[2] = lse3_2(A2 + B0[2], A1 + B1[1], A0 + B2[0]);
        D[3] = lae2(A2 + B1[2], A1 + B2[1]);
        D[4] = A2 + B2[2];
    };

    float Da[5], Db[5];
    depth4(g * 8, Da);
    depth4(g * 8 + 4, Db);
#pragma unroll
    for (int k = 0; k < 5; ++k) Bl[k][u] = Db[k];
    __syncthreads();

    if (u < 104) {
        // D8_m[u] = lse_j ( Da_j[u] + Db_{m-j}[u+j] ); u+j <= 107 < 128
        float d0 = Da[0] + Bl[0][u];
        float d1 = lae2(Da[0] + Bl[1][u], Da[1] + Bl[0][u + 1]);
        float d2 = lse3_2(Da[0] + Bl[2][u], Da[1] + Bl[1][u + 1],
                          Da[2] + Bl[0][u + 2]);
        float d3 = lae2(lae2(Da[0] + Bl[3][u], Da[1] + Bl[2][u + 1]),
                        lae2(Da[2] + Bl[1][u + 2], Da[3] + Bl[0][u + 3]));
        float d4 = lse5_2(Da[0] + Bl[4][u], Da[1] + Bl[3][u + 1],
                          Da[2] + Bl[2][u + 2], Da[3] + Bl[1][u + 3],
                          Da[4] + Bl[0][u + 4]);
        float d5 = lae2(lae2(Da[1] + Bl[4][u + 1], Da[2] + Bl[3][u + 2]),
                        lae2(Da[3] + Bl[2][u + 3], Da[4] + Bl[1][u + 4]));
        float d6 = lse3_2(Da[2] + Bl[4][u + 2], Da[3] + Bl[3][u + 3],
                          Da[4] + Bl[2][u + 4]);
        float d7 = lae2(Da[3] + Bl[4][u + 3], Da[4] + Bl[3][u + 4]);
        float d8 = Da[4] + Bl[4][u + 4];
        float* d = Dg + ((size_t)b * NG2 + g) * GS2;
        d[u] = d0;
        d[104 + u] = d1;
        d[208 + u] = d2;
        d[312 + u] = d3;
        d[416 + u] = d4;
        d[520 + u] = d5;
        d[624 + u] = d6;
        d[728 + u] = d7;
        d[832 + u] = d8;
    }
}

// ---- serial chain: 1 wave per batch, 64 banded-lse9 steps.
// Dg staged through LDS (4-group chunks, quad-buffered, counted vmcnt(30));
// register ring (depth 4) refills from LDS. No HBM on the serial path.
__global__ __launch_bounds__(64) void k_dpser(
    const float* __restrict__ Dg, const int* __restrict__ num_labels,
    float* __restrict__ out) {
    __shared__ __align__(16) float Dl[4 * CH2F];  // 4 x 15360B = 61440B
    const int b = blockIdx.x;
    const int lane = threadIdx.x;
    const char* Db = (const char*)(Dg + (size_t)b * NG2 * GS2);
    const int lo_u = lane;
    const int hi_u = 64 + ((lane < 33) ? lane : 0);

    // stage chunk q (groups q*4 .. q*4+3) into LDS buffer q%4
    auto stage = [&](int q) {
        const char* src = Db + (size_t)q * CH2B + lane * 16;
        char* dst = (char*)Dl + (q & 3) * CH2B + lane * 16;
#pragma unroll
        for (int i = 0; i < CH2I; ++i)
            async_copy16(src + i * 1024, dst + i * 1024);
    };

    stage(0);
    stage(1);
    stage(2);
    asm volatile("s_waitcnt vmcnt(30)" ::: "memory");  // chunk 0 landed

    float a_lo = (lane == 0) ? 0.f : NEG_INF;  // alpha[u=lane] (base-2)
    float a_hi = NEG_INF;                      // alpha[u=64+lane], lane<33

    float blo[4][9], bhi[4][9];
    // ring prologue: groups 0..3 (chunk 0, buffer 0)
#pragma unroll
    for (int g = 0; g < 4; ++g)
#pragma unroll
        for (int k = 0; k < 9; ++k) {
            blo[g][k] = Dl[g * GS2 + k * 104 + lo_u];
            bhi[g][k] = Dl[g * GS2 + k * 104 + hi_u];
        }

    for (int c = 0; c < NCH; ++c) {
        // issue chunk c+3 into buffer (c+3)%4 (last read during chunk c-1's
        // compute), then prove chunk c+1 landed (refills below read it).
        if (c + 3 < NCH) {
            stage(c + 3);
            asm volatile("s_waitcnt vmcnt(30)" ::: "memory");
        } else if (c + 2 < NCH) {
            asm volatile("s_waitcnt vmcnt(15)" ::: "memory");
        } else {
            asm volatile("s_waitcnt vmcnt(0)" ::: "memory");
        }
#pragma unroll
        for (int g8 = 0; g8 < CH2G; ++g8) {
            const int slot = g8;  // == g & 3
            float el[9], eh[9];
#pragma unroll
            for (int k = 0; k < 9; ++k) {
                el[k] = a_lo + blo[slot][k];
                eh[k] = a_hi + bhi[slot][k];
            }
            // refill slot with group g+4 from LDS (chunk c+1, proven landed)
            const int g = c * CH2G + g8;
            if (g + 4 < NG2) {
                const int q = g + 4;
                const int base = ((q >> 2) & 3) * CH2F + (q & 3) * GS2;
#pragma unroll
                for (int k = 0; k < 9; ++k) {
                    blo[slot][k] = Dl[base + k * 104 + lo_u];
                    bhi[slot][k] = Dl[base + k * 104 + hi_u];
                }
            }
            float ml[9], mh[9];
            ml[0] = el[0];
            mh[0] = eh[0];
#pragma unroll
            for (int k = 1; k < 9; ++k) {
                float su = __shfl_up(el[k], k);
                ml[k] = (lane >= k) ? su : NEG_INF;
                float sh = __shfl_up(eh[k], k);
                float xl = __shfl(el[k], 64 - k + lane);  // lo lanes 64-k..63
                mh[k] = (lane >= k) ? sh : xl;
            }
            a_lo = lse9_2(ml);
            float nh = lse9_2(mh);
            if (lane < 33) a_hi = nh;
        }
    }

    const int nl = num_labels[b];
    float res = (nl < 64) ? __shfl(a_lo, nl) : __shfl(a_hi, nl - 64);
    if (lane == 0) out[b] = -res * LN2;  // back to natural-log domain
}

extern "C" void kernel_launch(void* const* d_in, const int* in_sizes, int n_in,
                              void* d_out, int out_size, void* d_ws, size_t ws_size,
                              hipStream_t stream) {
    const float* frames = (const float*)d_in[0];
    const int* num_frames = (const int*)d_in[1];
    const int* labels = (const int*)d_in[2];
    const int* num_labels = (const int*)d_in[3];
    const float* Wf = (const float*)d_in[4];
    const float* E = (const float*)d_in[5];
    const float* Wo = (const float*)d_in[6];
    float* out = (float*)d_out;

    char* ws = (char*)d_ws;
    size_t off = 0;
    long* Wo_s = (long*)(ws + off); off += (size_t)17408 * 8;                 // 136 KiB
    f16* cemb = (f16*)(ws + off); off += (size_t)BB * NU * HH * 2;            // 388 KiB
    off = (off + 255) & ~(size_t)255;
    f16* fproj = (f16*)(ws + off); off += (size_t)BB * TT * HH * 2;           // 2 MiB
    off = (off + 255) & ~(size_t)255;
    f16* cl_arr = (f16*)(ws + off); off += (size_t)BB * TT * NU * 2 * 2;      // 776 KiB
    off = (off + 255) & ~(size_t)255;
    float* Dg = (float*)(ws + off); off += (size_t)BB * NG2 * GS2 * 4;        // 0.94 MiB

    hipLaunchKernelGGL(k_front, dim3(421), dim3(256), 0, stream,
                       frames, Wf, Wo, E, labels, fproj, Wo_s, cemb);
    hipLaunchKernelGGL(k_joint, dim3((TT * NU) / 64, BB), dim3(256), 0, stream,
                       fproj, cemb, Wo_s, labels, num_frames, cl_arr);
    hipLaunchKernelGGL(k_compact, dim3(NG2, BB), dim3(128), 0, stream,
                       cl_arr, num_frames, Dg);
    hipLaunchKernelGGL(k_dpser, dim3(BB), dim3(64), 0, stream,
                       Dg, num_labels, out);
}

// Round 10
// 165.061 us; speedup vs baseline: 1.1954x; 1.0214x over previous
//
#include <hip/hip_runtime.h>
#include <hip/hip_bf16.h>

// RecognitionLattice: RNN-T style lattice loss.
// k_front: fproj GEMM (fp32-Wf transpose staging via bf16x8 LDS stores) +
//          Wo->fp8 shuffle (NP=272 paired layout) + cemb gather (f16x2)
// -> k_joint: h=tanh(fproj+cemb) packed-f16 -> fp8 @ Wo_fp8, BK=64 K-loop.
//    4-wave blocks (64-row tiles), A-frags in registers, B double-buffered
//    via global_load_lds (b128 pairs), base-2 epilogue, 16B cl store.
//    (r6-exact: sits at the 128-VGPR cliff; structural edits regress)
// -> k_compact: depth-4 x2 + in-LDS composition -> depth-8 operators (9 bands)
// -> k_dpser: 1 wave/batch serial chain, 64 banded-lse9 steps, LDS-staged
//    (4-group chunks, quad-buffered, counted vmcnt(30)).
// ws: Dg ALIASES fproj (fproj dead after k_joint; stream-ordered) -> 3.3 MB.

#define BB 4
#define TT 512
#define UU 96
#define FF 512
#define HH 512
#define VV 256
#define NV (VV + 1)    // 257 vocab incl. blank
#define NU 97          // lattice rows per t
#define NP 272         // 17*16 padded N (257 -> 272)
#define NEG_INF (-1e30f)
#define LN2 0.6931471805599453f
#define WOSCL 64.0f    // Wo pre-scale into fp8 normal range
#define C2SCL 0.022542110f  // log2(e)/64: descale+base2 fold for the LSE
#define BCHUNK 17408   // bytes per 64-k B chunk = 64*272 fp8
#define BLONGS 2176    // longs per chunk
#define SPLANE 1088    // longs per 32-k sub-plane
// depth-8 operator bank
#define NG2 64         // groups of 8 t-steps
#define GS2 960        // padded floats per depth-8 operator (936 used)
#define CH2G 4                     // dpser: groups per staged chunk
#define CH2B (CH2G * GS2 * 4)      // 15360 bytes per chunk
#define CH2I (CH2B / 1024)         // 15 async copies per chunk
#define CH2F (CH2G * GS2)          // floats per chunk buffer
#define NCH 16                     // chunks

typedef _Float16 f16;
typedef __attribute__((ext_vector_type(2))) _Float16 f16x2;
typedef __attribute__((ext_vector_type(8))) _Float16 f16x8;
typedef __attribute__((ext_vector_type(2))) long longx2;
typedef __bf16 bf16;
typedef __bf16 bf16x8 __attribute__((ext_vector_type(8)));
typedef float f32x4 __attribute__((ext_vector_type(4)));

__device__ __forceinline__ f16x8 splat8(float s) {
    f16 v = (f16)s;
    f16x8 r = {v, v, v, v, v, v, v, v};
    return r;
}

// tanh via clamped odd polynomial in PACKED f16 (v_pk_* dual-issue), then
// fp8 e4m3 pack. Max poly err ~0.007 on [-2,2]; f16 intermediate err ~1e-3
// << fp8 output quantization.
__device__ __forceinline__ long tanh_pack8(f16x8 fv8, f16x8 cv8) {
    f16x8 x = fv8 + cv8;
    x = __builtin_elementwise_min(__builtin_elementwise_max(x, splat8(-2.0f)),
                                  splat8(2.0f));
    f16x8 y = x * x;
    f16x8 q = y * splat8(-0.0067528f) + splat8(0.0700672f);
    q = y * q + splat8(-0.301720f);
    q = y * q + splat8(1.0f);
    f16x8 t = x * q;
    int lo = 0, hi = 0;
    lo = __builtin_amdgcn_cvt_pk_fp8_f32((float)t[0], (float)t[1], lo, false);
    lo = __builtin_amdgcn_cvt_pk_fp8_f32((float)t[2], (float)t[3], lo, true);
    hi = __builtin_amdgcn_cvt_pk_fp8_f32((float)t[4], (float)t[5], hi, false);
    hi = __builtin_amdgcn_cvt_pk_fp8_f32((float)t[6], (float)t[7], hi, true);
    return (long)(((unsigned long long)(unsigned int)lo) |
                  (((unsigned long long)(unsigned int)hi) << 32));
}

// pack 8 floats -> 8 fp8 e4m3 (for Wo prep)
__device__ __forceinline__ long pack_fp8x8(const float* v) {
    int lo = 0, hi = 0;
    lo = __builtin_amdgcn_cvt_pk_fp8_f32(v[0], v[1], lo, false);
    lo = __builtin_amdgcn_cvt_pk_fp8_f32(v[2], v[3], lo, true);
    hi = __builtin_amdgcn_cvt_pk_fp8_f32(v[4], v[5], hi, false);
    hi = __builtin_amdgcn_cvt_pk_fp8_f32(v[6], v[7], hi, true);
    return (long)(((unsigned long long)(unsigned int)lo) |
                  (((unsigned long long)(unsigned int)hi) << 32));
}

// base-2 log-domain ops
__device__ __forceinline__ float lae2(float x, float y) {
    float m = fmaxf(x, y);
    float d = fminf(x, y) - m;
    return m + __builtin_amdgcn_logf(1.0f + __builtin_amdgcn_exp2f(d));
}

__device__ __forceinline__ float lse3_2(float x, float y, float z) {
    float m = fmaxf(fmaxf(x, y), z);
    float s = __builtin_amdgcn_exp2f(x - m) + __builtin_amdgcn_exp2f(y - m) +
              __builtin_amdgcn_exp2f(z - m);
    return m + __builtin_amdgcn_logf(s);
}

__device__ __forceinline__ float lse5_2(float a, float b, float c, float d, float e) {
    float m = fmaxf(fmaxf(fmaxf(a, b), fmaxf(c, d)), e);
    float s = __builtin_amdgcn_exp2f(a - m) + __builtin_amdgcn_exp2f(b - m) +
              __builtin_amdgcn_exp2f(c - m) + __builtin_amdgcn_exp2f(d - m) +
              __builtin_amdgcn_exp2f(e - m);
    return m + __builtin_amdgcn_logf(s);
}

__device__ __forceinline__ float lse9_2(const float* v) {
    float m1 = fmaxf(fmaxf(v[0], v[1]), v[2]);
    float m2 = fmaxf(fmaxf(v[3], v[4]), v[5]);
    float m3 = fmaxf(fmaxf(v[6], v[7]), v[8]);
    float m = fmaxf(fmaxf(m1, m2), m3);
    float s = 0.f;
#pragma unroll
    for (int k = 0; k < 9; ++k) s += __builtin_amdgcn_exp2f(v[k] - m);
    return m + __builtin_amdgcn_logf(s);
}

__device__ __forceinline__ void async_copy16(const void* g, void* l) {
    __builtin_amdgcn_global_load_lds(
        (const __attribute__((address_space(1))) unsigned int*)g,
        (__attribute__((address_space(3))) unsigned int*)l, 16, 0, 0);
}

// ---- front: fproj GEMM + Wo->fp8 shuffle + cemb gather
__global__ __launch_bounds__(256, 2) void k_front(
    const float* __restrict__ frames, const float* __restrict__ Wf,
    const float* __restrict__ Wo, const float* __restrict__ E,
    const int* __restrict__ labels, f16* __restrict__ fproj,
    long* __restrict__ Wo_s, f16* __restrict__ cemb) {
    __shared__ bf16 Alds[64 * 40];
    __shared__ bf16 Blds[64 * 40];
    const int blk = blockIdx.x;
    const int tid = threadIdx.x;

    if (blk < 256) {
        const int r0 = (blk & 31) * 64;
        const int n0 = (blk >> 5) * 64;
        const int lane = tid & 63, w = tid >> 6;
        const int c = lane & 15, g = lane >> 4;

        const int srow = tid >> 2, sko = (tid & 3) * 8;
        const float* fptr = frames + (size_t)(r0 + srow) * FF + sko;
        const int q = tid >> 6, c64 = tid & 63;  // B-transpose staging coords

        f32x4 acc[4];
#pragma unroll
        for (int j = 0; j < 4; ++j) acc[j] = (f32x4){0.f, 0.f, 0.f, 0.f};

        for (int kt = 0; kt < FF; kt += 32) {
            float4 f1 = *(const float4*)(fptr + kt);
            float4 f2 = *(const float4*)(fptr + kt + 4);
            bf16x8 av = {(bf16)f1.x, (bf16)f1.y, (bf16)f1.z, (bf16)f1.w,
                         (bf16)f2.x, (bf16)f2.y, (bf16)f2.z, (bf16)f2.w};
            *(bf16x8*)&Alds[srow * 40 + sko] = av;
            bf16x8 bv8;
#pragma unroll
            for (int p = 0; p < 8; ++p) {
                float v = Wf[(size_t)(kt + q * 8 + p) * HH + n0 + c64];
                bv8[p] = (bf16)v;
            }
            *(bf16x8*)&Blds[c64 * 40 + q * 8] = bv8;  // one 16B LDS store
            __syncthreads();
            const int m = w * 16;
            bf16x8 af = *(const bf16x8*)&Alds[(m + c) * 40 + g * 8];
#pragma unroll
            for (int j = 0; j < 4; ++j) {
                bf16x8 bv = *(const bf16x8*)&Blds[(j * 16 + c) * 40 + g * 8];
                acc[j] = __builtin_amdgcn_mfma_f32_16x16x32_bf16(af, bv, acc[j], 0, 0, 0);
            }
            __syncthreads();
        }
        const int m = w * 16;
#pragma unroll
        for (int j = 0; j < 4; ++j)
#pragma unroll
            for (int r = 0; r < 4; ++r)
                fproj[(size_t)(r0 + m + g * 4 + r) * HH + n0 + j * 16 + c] = (f16)acc[j][r];
    } else if (blk < 324) {
        // Wo -> fp8, PAIRED layout: within plane (k32,g), position
        //   pos = (j>>1)*32 + c*2 + (j&1)  for j=0..15 (cols j*16+c)
        //   pos = 256 + c                  for j=16    (cols 256+c)
        // so k_joint reads (2p,2p+1) as one ds_read_b128 per lane.
        int idx = (blk - 256) * 256 + tid;  // 0..17407
        int pos = idx % NP;
        int plane = idx / NP;
        int g = plane & 3;
        int k32 = plane >> 2;
        int n;
        if (pos < 256) {
            int j = ((pos >> 5) << 1) | (pos & 1);
            int cc = (pos >> 1) & 15;
            n = j * 16 + cc;
        } else {
            n = 256 + (pos - 256);
        }
        float v[8];
#pragma unroll
        for (int e = 0; e < 8; ++e) {
            int k = k32 * 32 + g * 8 + e;
            v[e] = (n < NV) ? Wo[k * NV + n] * WOSCL : 0.f;
        }
        Wo_s[idx] = pack_fp8x8(v);
    } else {
        int u = blk - 324;  // 0..96
        for (int b = 0; b < BB; ++b) {
            int ctx = (u == 0) ? 0 : labels[b * UU + (u - 1)];
            const float2* src = (const float2*)(E + (size_t)ctx * HH);
            f16x2* dst = (f16x2*)(cemb + ((size_t)b * NU + u) * HH);
            float2 v = src[tid];          // HH/2 = 256 pairs = one per thread
            f16x2 o;
            o.x = (f16)v.x;
            o.y = (f16)v.y;
            dst[tid] = o;
        }
    }
}

// ---- joint: logits = tanh(fproj[t]+cemb[u]) @ Wo  [fp8 MFMA, BK=64 K-loop]
// r6-exact. grid (776, B), block 256 = 4 waves = 4 M-slots of 16 rows.
__global__ __launch_bounds__(256, 4) void k_joint(
    const f16* __restrict__ fproj, const f16* __restrict__ cemb,
    const long* __restrict__ Wo_s, const int* __restrict__ labels,
    const int* __restrict__ num_frames, f16* __restrict__ cl_arr) {
    __shared__ __align__(16) long B_s8[2][BLONGS];  // 2 x 17408 B

    const int tid = threadIdx.x;
    const int b = blockIdx.y;
    const int r0 = blockIdx.x * 64;
    const int nf = num_frames[b];
    if (r0 / NU >= nf) return;  // whole tile beyond active frames: outputs unused

    const int lane = tid & 63, w = tid >> 6;
    const int c = lane & 15, g = lane >> 4;

    const int gr = r0 + w * 16 + c;
    const int at = gr / NU, au = gr - at * NU;
    const f16* pf = fproj + ((size_t)(b * TT + at)) * HH + g * 8;
    const f16* pc = cemb + ((size_t)(b * NU + au)) * HH + g * 8;
    const char* wsrcB = (const char*)Wo_s + lane * 16;

    f32x4 acc[17];
#pragma unroll
    for (int j = 0; j < 17; ++j) acc[j] = (f32x4){0.f, 0.f, 0.f, 0.f};

    const int bB0p = g * NP + (c << 1);   // paired-B base (longs)
    const int bB16 = g * NP + 256 + c;    // j=16 tail (longs)

    long a0, a1;  // current chunk A-frags

    // ---- prologue: stage B chunk 0, compute A-frags for chunk 0 ----
    {
        for (int ch = w; ch < 17; ch += 4)
            async_copy16(wsrcB + ch * 1024, (char*)&B_s8[0][0] + ch * 1024 + lane * 16);
        f16x8 fv0 = *(const f16x8*)pf;
        f16x8 cv0 = *(const f16x8*)pc;
        f16x8 fv1 = *(const f16x8*)(pf + 32);
        f16x8 cv1 = *(const f16x8*)(pc + 32);
        a0 = tanh_pack8(fv0, cv0);
        a1 = tanh_pack8(fv1, cv1);
        __syncthreads();
    }

    // ---- main loop: one barrier per 64-k chunk ----
    for (int i = 0; i < 8; ++i) {
        const int cur = i & 1, nxt = cur ^ 1;
        f16x8 fv0, cv0, fv1, cv1;
        if (i < 7) {
            const char* wk = wsrcB + (size_t)(i + 1) * BCHUNK;
            for (int ch = w; ch < 17; ch += 4)
                async_copy16(wk + ch * 1024, (char*)&B_s8[nxt][0] + ch * 1024 + lane * 16);
            const int kt = (i + 1) * 64;
            fv0 = *(const f16x8*)(pf + kt);
            cv0 = *(const f16x8*)(pc + kt);
            fv1 = *(const f16x8*)(pf + kt + 32);
            cv1 = *(const f16x8*)(pc + kt + 32);
        }
        __builtin_amdgcn_s_setprio(1);
#pragma unroll
        for (int p = 0; p < 8; ++p) {
            longx2 bv = *(const longx2*)&B_s8[cur][bB0p + p * 32];
            acc[2 * p] = __builtin_amdgcn_mfma_f32_16x16x32_fp8_fp8(a0, bv[0], acc[2 * p], 0, 0, 0);
            acc[2 * p + 1] = __builtin_amdgcn_mfma_f32_16x16x32_fp8_fp8(a0, bv[1], acc[2 * p + 1], 0, 0, 0);
        }
        acc[16] = __builtin_amdgcn_mfma_f32_16x16x32_fp8_fp8(a0, B_s8[cur][bB16], acc[16], 0, 0, 0);
        __builtin_amdgcn_s_setprio(0);
        long a0n, a1n;
        if (i < 7) {
            a0n = tanh_pack8(fv0, cv0);
            a1n = tanh_pack8(fv1, cv1);
        }
        __builtin_amdgcn_s_setprio(1);
#pragma unroll
        for (int p = 0; p < 8; ++p) {
            longx2 bv = *(const longx2*)&B_s8[cur][SPLANE + bB0p + p * 32];
            acc[2 * p] = __builtin_amdgcn_mfma_f32_16x16x32_fp8_fp8(a1, bv[0], acc[2 * p], 0, 0, 0);
            acc[2 * p + 1] = __builtin_amdgcn_mfma_f32_16x16x32_fp8_fp8(a1, bv[1], acc[2 * p + 1], 0, 0, 0);
        }
        acc[16] = __builtin_amdgcn_mfma_f32_16x16x32_fp8_fp8(a1, B_s8[cur][SPLANE + bB16], acc[16], 0, 0, 0);
        __builtin_amdgcn_s_setprio(0);
        if (i < 7) {
            a0 = a0n;
            a1 = a1n;
            __syncthreads();
        }
    }

    // epilogue: wave owns 16 complete rows -> fully in-wave LSE, base-2.
    const int rbase = r0 + w * 16 + g * 4;
    f16x8 ovs;
#pragma unroll
    for (int r = 0; r < 4; ++r) {
        const int grr = rbase + r;
        const int u = grr - (grr / NU) * NU;

        float mx = NEG_INF;
#pragma unroll
        for (int j = 0; j < 17; ++j) {
            int col = j * 16 + c;
            if (col < NV) mx = fmaxf(mx, acc[j][r]);
        }
#pragma unroll
        for (int s = 1; s < 16; s <<= 1) mx = fmaxf(mx, __shfl_xor(mx, s));
        float mxc = mx * C2SCL;
        float sum = 0.f;
#pragma unroll
        for (int j = 0; j < 17; ++j) {
            int col = j * 16 + c;
            if (col < NV)
                sum += __builtin_amdgcn_exp2f(fmaf(acc[j][r], C2SCL, -mxc));
        }
#pragma unroll
        for (int s = 1; s < 16; s <<= 1) sum += __shfl_xor(sum, s);
        float lse2 = mxc + __builtin_amdgcn_logf(sum);

        float blankv = __shfl(acc[0][r], lane & 48);  // col 0 (raw domain)
        int L = (u < UU) ? labels[b * UU + u] : 0;    // 1..256 (or dummy 0)
        int jl = L >> 4;
        float v = acc[0][r];
#pragma unroll
        for (int j = 1; j < 17; ++j)
            if (jl == j) v = acc[j][r];               // static-index select
        float lexv = __shfl(v, (lane & 48) | (L & 15));

        ovs[2 * r] = (f16)fmaf(blankv, C2SCL, -lse2);
        ovs[2 * r + 1] = (u < UU) ? (f16)fmaf(lexv, C2SCL, -lse2) : (f16)0.f;
    }
    if (c == 0)
        *(f16x8*)&cl_arr[((size_t)b * TT * NU + rbase) * 2] = ovs;
}

// ---- depth-8 compaction: grid (NG2, BB), block 128 (one thread per u).
// Two depth-4 operators composed in LDS -> 9-band depth-8 operator.
__global__ __launch_bounds__(128) void k_compact(
    const f16* __restrict__ cl, const int* __restrict__ num_frames,
    float* __restrict__ Dg) {
    __shared__ float Bl[5][128];
    const int g = blockIdx.x;   // 0..63 (8-frame group)
    const int b = blockIdx.y;
    const int u = threadIdx.x;  // 0..127
    const int nf = num_frames[b];
    const f16x2* P = (const f16x2*)(cl + (size_t)b * TT * NU * 2);

    auto fetch = [&](int t, int uu, float& bb, float& ll) {
        if (uu <= UU) {
            f16x2 z = P[t * NU + uu];
            bool act = t < nf;
            bb = act ? (float)z.x : 0.f;                      // base-2 already
            ll = (act && uu < UU) ? (float)z.y : NEG_INF;
        } else {
            bb = NEG_INF;
            ll = NEG_INF;
        }
    };

    auto depth4 = [&](int t0, float* D) {
        float b0, l0, b1u, l1u, b1u1, l1u1;
        fetch(t0, u, b0, l0);
        fetch(t0 + 1, u, b1u, l1u);
        fetch(t0 + 1, u + 1, b1u1, l1u1);
        float A0 = b0 + b1u;
        float A1 = lae2(l0 + b1u1, b0 + l1u);
        float A2 = l0 + l1u1;
        float B0[3], B1[3], B2[3];
#pragma unroll
        for (int j = 0; j < 3; ++j) {
            float b2v, l2v, b3v, l3v, b3n, l3n;
            fetch(t0 + 2, u + j, b2v, l2v);
            fetch(t0 + 3, u + j, b3v, l3v);
            fetch(t0 + 3, u + j + 1, b3n, l3n);
            B0[j] = b2v + b3v;
            B1[j] = lae2(l2v + b3n, b2v + l3v);
            B2[j] = l2v + l3n;
        }
        D[0] = A0 + B0[0];
        D[1] = lae2(A1 + B0[1], A0 + B1[0]);
        D[2] = lse3_2(A2 + B0[2], A1 + B1[1], A0 + B2[0]);
        D[3] = lae2(A2 + B1[2], A1 + B2[1]);
        D[4] = A2 + B2[2];
    };

    float Da[5], Db[5];
    depth4(g * 8, Da);
    depth4(g * 8 + 4, Db);
#pragma unroll
    for (int k = 0; k < 5; ++k) Bl[k][u] = Db[k];
    __syncthreads();

    if (u < 104) {
        // D8_m[u] = lse_j ( Da_j[u] + Db_{m-j}[u+j] ); u+j <= 107 < 128
        float d0 = Da[0] + Bl[0][u];
        float d1 = lae2(Da[0] + Bl[1][u], Da[1] + Bl[0][u + 1]);
        float d2 = lse3_2(Da[0] + Bl[2][u], Da[1] + Bl[1][u + 1],
                          Da[2] + Bl[0][u + 2]);
        float d3 = lae2(lae2(Da[0] + Bl[3][u], Da[1] + Bl[2][u + 1]),
                        lae2(Da[2] + Bl[1][u + 2], Da[3] + Bl[0][u + 3]));
        float d4 = lse5_2(Da[0] + Bl[4][u], Da[1] + Bl[3][u + 1],
                          Da[2] + Bl[2][u + 2], Da[3] + Bl[1][u + 3],
                          Da[4] + Bl[0][u + 4]);
        float d5 = lae2(lae2(Da[1] + Bl[4][u + 1], Da[2] + Bl[3][u + 2]),
                        lae2(Da[3] + Bl[2][u + 3], Da[4] + Bl[1][u + 4]));
        float d6 = lse3_2(Da[2] + Bl[4][u + 2], Da[3] + Bl[3][u + 3],
                          Da[4] + Bl[2][u + 4]);
        float d7 = lae2(Da[3] + Bl[4][u + 3], Da[4] + Bl[3][u + 4]);
        float d8 = Da[4] + Bl[4][u + 4];
        float* d = Dg + ((size_t)b * NG2 + g) * GS2;
        d[u] = d0;
        d[104 + u] = d1;
        d[208 + u] = d2;
        d[312 + u] = d3;
        d[416 + u] = d4;
        d[520 + u] = d5;
        d[624 + u] = d6;
        d[728 + u] = d7;
        d[832 + u] = d8;
    }
}

// ---- serial chain: 1 wave per batch, 64 banded-lse9 steps.
// Dg staged through LDS (4-group chunks, quad-buffered, counted vmcnt(30));
// register ring (depth 4) refills from LDS. No HBM on the serial path.
__global__ __launch_bounds__(64) void k_dpser(
    const float* __restrict__ Dg, const int* __restrict__ num_labels,
    float* __restrict__ out) {
    __shared__ __align__(16) float Dl[4 * CH2F];  // 4 x 15360B = 61440B
    const int b = blockIdx.x;
    const int lane = threadIdx.x;
    const char* Db = (const char*)(Dg + (size_t)b * NG2 * GS2);
    const int lo_u = lane;
    const int hi_u = 64 + ((lane < 33) ? lane : 0);

    // stage chunk q (groups q*4 .. q*4+3) into LDS buffer q%4
    auto stage = [&](int q) {
        const char* src = Db + (size_t)q * CH2B + lane * 16;
        char* dst = (char*)Dl + (q & 3) * CH2B + lane * 16;
#pragma unroll
        for (int i = 0; i < CH2I; ++i)
            async_copy16(src + i * 1024, dst + i * 1024);
    };

    stage(0);
    stage(1);
    stage(2);
    asm volatile("s_waitcnt vmcnt(30)" ::: "memory");  // chunk 0 landed

    float a_lo = (lane == 0) ? 0.f : NEG_INF;  // alpha[u=lane] (base-2)
    float a_hi = NEG_INF;                      // alpha[u=64+lane], lane<33

    float blo[4][9], bhi[4][9];
    // ring prologue: groups 0..3 (chunk 0, buffer 0)
#pragma unroll
    for (int g = 0; g < 4; ++g)
#pragma unroll
        for (int k = 0; k < 9; ++k) {
            blo[g][k] = Dl[g * GS2 + k * 104 + lo_u];
            bhi[g][k] = Dl[g * GS2 + k * 104 + hi_u];
        }

    for (int c = 0; c < NCH; ++c) {
        // issue chunk c+3 into buffer (c+3)%4 (last read during chunk c-1's
        // compute), then prove chunk c+1 landed (refills below read it).
        if (c + 3 < NCH) {
            stage(c + 3);
            asm volatile("s_waitcnt vmcnt(30)" ::: "memory");
        } else if (c + 2 < NCH) {
            asm volatile("s_waitcnt vmcnt(15)" ::: "memory");
        } else {
            asm volatile("s_waitcnt vmcnt(0)" ::: "memory");
        }
#pragma unroll
        for (int g8 = 0; g8 < CH2G; ++g8) {
            const int slot = g8;  // == g & 3
            float el[9], eh[9];
#pragma unroll
            for (int k = 0; k < 9; ++k) {
                el[k] = a_lo + blo[slot][k];
                eh[k] = a_hi + bhi[slot][k];
            }
            // refill slot with group g+4 from LDS (chunk c+1, proven landed)
            const int g = c * CH2G + g8;
            if (g + 4 < NG2) {
                const int q = g + 4;
                const int base = ((q >> 2) & 3) * CH2F + (q & 3) * GS2;
#pragma unroll
                for (int k = 0; k < 9; ++k) {
                    blo[slot][k] = Dl[base + k * 104 + lo_u];
                    bhi[slot][k] = Dl[base + k * 104 + hi_u];
                }
            }
            float ml[9], mh[9];
            ml[0] = el[0];
            mh[0] = eh[0];
#pragma unroll
            for (int k = 1; k < 9; ++k) {
                float su = __shfl_up(el[k], k);
                ml[k] = (lane >= k) ? su : NEG_INF;
                float sh = __shfl_up(eh[k], k);
                float xl = __shfl(el[k], 64 - k + lane);  // lo lanes 64-k..63
                mh[k] = (lane >= k) ? sh : xl;
            }
            a_lo = lse9_2(ml);
            float nh = lse9_2(mh);
            if (lane < 33) a_hi = nh;
        }
    }

    const int nl = num_labels[b];
    float res = (nl < 64) ? __shfl(a_lo, nl) : __shfl(a_hi, nl - 64);
    if (lane == 0) out[b] = -res * LN2;  // back to natural-log domain
}

extern "C" void kernel_launch(void* const* d_in, const int* in_sizes, int n_in,
                              void* d_out, int out_size, void* d_ws, size_t ws_size,
                              hipStream_t stream) {
    const float* frames = (const float*)d_in[0];
    const int* num_frames = (const int*)d_in[1];
    const int* labels = (const int*)d_in[2];
    const int* num_labels = (const int*)d_in[3];
    const float* Wf = (const float*)d_in[4];
    const float* E = (const float*)d_in[5];
    const float* Wo = (const float*)d_in[6];
    float* out = (float*)d_out;

    char* ws = (char*)d_ws;
    size_t off = 0;
    long* Wo_s = (long*)(ws + off); off += (size_t)17408 * 8;                 // 136 KiB
    f16* cemb = (f16*)(ws + off); off += (size_t)BB * NU * HH * 2;            // 388 KiB
    off = (off + 255) & ~(size_t)255;
    f16* fproj = (f16*)(ws + off);
    float* Dg = (float*)(ws + off);  // ALIAS: Dg reuses fproj's region
    off += (size_t)BB * TT * HH * 2;                                          // 2 MiB
    off = (off + 255) & ~(size_t)255;
    f16* cl_arr = (f16*)(ws + off); off += (size_t)BB * TT * NU * 2 * 2;      // 776 KiB
    // total ~3.3 MB (Dg's 0.94 MB folded into fproj's dead region)

    hipLaunchKernelGGL(k_front, dim3(421), dim3(256), 0, stream,
                       frames, Wf, Wo, E, labels, fproj, Wo_s, cemb);
    hipLaunchKernelGGL(k_joint, dim3((TT * NU) / 64, BB), dim3(256), 0, stream,
                       fproj, cemb, Wo_s, labels, num_frames, cl_arr);
    hipLaunchKernelGGL(k_compact, dim3(NG2, BB), dim3(128), 0, stream,
                       cl_arr, num_frames, Dg);
    hipLaunchKernelGGL(k_dpser, dim3(BB), dim3(64), 0, stream,
                       Dg, num_labels, out);
}